// Round 1
// baseline (1693.813 us; speedup 1.0000x reference)
//
#include <hip/hip_runtime.h>
#include <cstdio>

#define ALPHAC 1.702f
#define LIMITC 7.0f

constexpr int cE = 8, cT = 4096, cH = 2048, cI = 2048;

typedef short bf16x8 __attribute__((ext_vector_type(8)));
typedef float f32x4 __attribute__((ext_vector_type(4)));

__device__ __forceinline__ unsigned short f2bf(float f) {
  union { float f; unsigned int u; } v; v.f = f;
  unsigned int r = v.u + 0x7fffu + ((v.u >> 16) & 1u);
  return (unsigned short)(r >> 16);
}

__device__ __forceinline__ void gl_lds16(const void* g, void* l) {
  __builtin_amdgcn_global_load_lds(
      (const __attribute__((address_space(1))) unsigned int*)g,
      (__attribute__((address_space(3))) unsigned int*)l, 16, 0, 0);
}

// ---------------- conversion: fp32 -> bf16, straight copy ----------------
__global__ void conv_f2bf(const float* __restrict__ in, unsigned short* __restrict__ out,
                          size_t n) {
  size_t i = ((size_t)blockIdx.x * blockDim.x + threadIdx.x) * 4;
  size_t stride = (size_t)gridDim.x * blockDim.x * 4;
  for (; i < n; i += stride) {
    float4 v = *(const float4*)(in + i);
    ushort4 o;
    o.x = f2bf(v.x); o.y = f2bf(v.y); o.z = f2bf(v.z); o.w = f2bf(v.w);
    *(ushort4*)(out + i) = o;
  }
}

// ---- transpose (+optional de-interleave) fp32 [E][K][C] -> bf16 [E][C][K] ----
// deintI > 0: output row j < deintI maps to input col 2j (gate), j >= deintI -> 2(j-deintI)+1 (up)
__global__ void transpose_conv(const float* __restrict__ in, unsigned short* __restrict__ out,
                               int K, int C, int deintI) {
  __shared__ float tile[32][33];
  const int e = blockIdx.z;
  const int j0 = blockIdx.x * 32;
  const int k0 = blockIdx.y * 32;
  const int tx = threadIdx.x, ty = threadIdx.y;
  const float* inp = in + (size_t)e * K * C;
  unsigned short* outp = out + (size_t)e * C * K;
  const int j = j0 + tx;
  const int c = (deintI > 0) ? ((j < deintI) ? 2 * j : 2 * (j - deintI) + 1) : j;
#pragma unroll
  for (int i = 0; i < 4; ++i) {
    int k = k0 + ty + i * 8;
    tile[ty + i * 8][tx] = inp[(size_t)k * C + c];
  }
  __syncthreads();
#pragma unroll
  for (int i = 0; i < 4; ++i) {
    int jj = j0 + ty + i * 8;
    outp[(size_t)jj * K + k0 + tx] = f2bf(tile[tx][ty + i * 8]);
  }
}

// ---------------- GEMM1: h = GLU(x @ W1) fused epilogue ----------------
// xb:  [E][T][H]   bf16 (row, K-contig)
// w1t: [E][2I][H]  bf16 (rows 0..I-1 = gate cols, I..2I-1 = up cols; K-contig)
// h:   [E][T][I]   bf16
__global__ __launch_bounds__(256, 2) void gemm1_kernel(
    const unsigned short* __restrict__ xb, const unsigned short* __restrict__ w1t,
    const float* __restrict__ gub, unsigned short* __restrict__ h) {
  __shared__ unsigned short As[128 * 64];
  __shared__ unsigned short Bg[128 * 64];
  __shared__ unsigned short Bu[128 * 64];
  const int e = blockIdx.z;
  const int j0 = blockIdx.x * 128;  // h-column tile
  const int m0 = blockIdx.y * 128;  // row tile
  const int tid = threadIdx.x;
  const int lane = tid & 63;
  const int wid = tid >> 6;
  const int wr = wid >> 1, wc = wid & 1;
  const int r_l = lane >> 3;        // staging: row-within-8
  const int c8 = (lane & 7) * 8;    // staging: bf16 col offset (16B chunk)
  const int fr = lane & 15;         // fragment row/col
  const int fq = lane >> 4;         // fragment quadrant 0..3

  const size_t xbase = (size_t)e * cT * cH + (size_t)m0 * cH;
  const size_t gbase = (size_t)e * (2 * cI) * cH + (size_t)j0 * cH;
  const size_t ubase = (size_t)e * (2 * cI) * cH + (size_t)(cI + j0) * cH;

  f32x4 accg[4][4] = {};
  f32x4 accu[4][4] = {};

  for (int kt = 0; kt < cH / 64; ++kt) {
    const int k0 = kt * 64;
#pragma unroll
    for (int i = 0; i < 4; ++i) {
      int row = wid * 32 + i * 8;
      gl_lds16(xb + xbase + (size_t)(row + r_l) * cH + k0 + c8, As + row * 64);
      gl_lds16(w1t + gbase + (size_t)(row + r_l) * cH + k0 + c8, Bg + row * 64);
      gl_lds16(w1t + ubase + (size_t)(row + r_l) * cH + k0 + c8, Bu + row * 64);
    }
    __syncthreads();
#pragma unroll
    for (int kk = 0; kk < 2; ++kk) {
      bf16x8 a[4], bg[4], bu[4];
#pragma unroll
      for (int m = 0; m < 4; ++m)
        a[m] = *(const bf16x8*)&As[(wr * 64 + m * 16 + fr) * 64 + kk * 32 + fq * 8];
#pragma unroll
      for (int n = 0; n < 4; ++n) {
        bg[n] = *(const bf16x8*)&Bg[(wc * 64 + n * 16 + fr) * 64 + kk * 32 + fq * 8];
        bu[n] = *(const bf16x8*)&Bu[(wc * 64 + n * 16 + fr) * 64 + kk * 32 + fq * 8];
      }
#pragma unroll
      for (int m = 0; m < 4; ++m)
#pragma unroll
        for (int n = 0; n < 4; ++n) {
          accg[m][n] = __builtin_amdgcn_mfma_f32_16x16x32_bf16(a[m], bg[n], accg[m][n], 0, 0, 0);
          accu[m][n] = __builtin_amdgcn_mfma_f32_16x16x32_bf16(a[m], bu[n], accu[m][n], 0, 0, 0);
        }
    }
    __syncthreads();
  }

  // epilogue: bias + clamp + GLU, write bf16 h
  unsigned short* hp = h + (size_t)e * cT * cI;
  const float* gb = gub + (size_t)e * 2 * cI;
#pragma unroll
  for (int m = 0; m < 4; ++m) {
#pragma unroll
    for (int n = 0; n < 4; ++n) {
      int col = j0 + wc * 64 + n * 16 + fr;
      float bgv = gb[2 * col];
      float buv = gb[2 * col + 1];
#pragma unroll
      for (int r = 0; r < 4; ++r) {
        int row = m0 + wr * 64 + m * 16 + fq * 4 + r;
        float g = accg[m][n][r] + bgv;
        float u = accu[m][n][r] + buv;
        g = fminf(g, LIMITC);
        u = fminf(fmaxf(u, -LIMITC), LIMITC);
        float glu = g / (1.0f + __expf(-ALPHAC * g));
        float hv = (u + 1.0f) * glu;
        hp[(size_t)row * cI + col] = f2bf(hv);
      }
    }
  }
}

// ---------------- GEMM2: out = h @ W2 + bias (fp32 out) ----------------
// hb:  [E][T][I] bf16 ; w2t: [E][H][I] bf16 (K-contig) ; out: [E][T][H] fp32
__global__ __launch_bounds__(256, 2) void gemm2_kernel(
    const unsigned short* __restrict__ hb, const unsigned short* __restrict__ w2t,
    const float* __restrict__ db, float* __restrict__ out) {
  __shared__ unsigned short As[128 * 64];
  __shared__ unsigned short Bs[128 * 64];
  const int e = blockIdx.z;
  const int n0 = blockIdx.x * 128;
  const int m0 = blockIdx.y * 128;
  const int tid = threadIdx.x;
  const int lane = tid & 63;
  const int wid = tid >> 6;
  const int wr = wid >> 1, wc = wid & 1;
  const int r_l = lane >> 3;
  const int c8 = (lane & 7) * 8;
  const int fr = lane & 15;
  const int fq = lane >> 4;

  const size_t abase = (size_t)e * cT * cI + (size_t)m0 * cI;
  const size_t bbase = (size_t)e * cH * cI + (size_t)n0 * cI;

  f32x4 acc[4][4] = {};

  for (int kt = 0; kt < cI / 64; ++kt) {
    const int k0 = kt * 64;
#pragma unroll
    for (int i = 0; i < 4; ++i) {
      int row = wid * 32 + i * 8;
      gl_lds16(hb + abase + (size_t)(row + r_l) * cI + k0 + c8, As + row * 64);
      gl_lds16(w2t + bbase + (size_t)(row + r_l) * cI + k0 + c8, Bs + row * 64);
    }
    __syncthreads();
#pragma unroll
    for (int kk = 0; kk < 2; ++kk) {
      bf16x8 a[4], b[4];
#pragma unroll
      for (int m = 0; m < 4; ++m)
        a[m] = *(const bf16x8*)&As[(wr * 64 + m * 16 + fr) * 64 + kk * 32 + fq * 8];
#pragma unroll
      for (int n = 0; n < 4; ++n)
        b[n] = *(const bf16x8*)&Bs[(wc * 64 + n * 16 + fr) * 64 + kk * 32 + fq * 8];
#pragma unroll
      for (int m = 0; m < 4; ++m)
#pragma unroll
        for (int n = 0; n < 4; ++n)
          acc[m][n] = __builtin_amdgcn_mfma_f32_16x16x32_bf16(a[m], b[n], acc[m][n], 0, 0, 0);
    }
    __syncthreads();
  }

  float* op = out + (size_t)e * cT * cH;
  const float* dbp = db + (size_t)e * cH;
#pragma unroll
  for (int m = 0; m < 4; ++m) {
#pragma unroll
    for (int n = 0; n < 4; ++n) {
      int col = n0 + wc * 64 + n * 16 + fr;
      float bv = dbp[col];
#pragma unroll
      for (int r = 0; r < 4; ++r) {
        int row = m0 + wr * 64 + m * 16 + fq * 4 + r;
        op[(size_t)row * cH + col] = acc[m][n][r] + bv;
      }
    }
  }
}

extern "C" void kernel_launch(void* const* d_in, const int* in_sizes, int n_in,
                              void* d_out, int out_size, void* d_ws, size_t ws_size,
                              hipStream_t stream) {
  const float* x   = (const float*)d_in[0];
  const float* gup = (const float*)d_in[1];
  const float* gub = (const float*)d_in[2];
  const float* dwn = (const float*)d_in[3];
  const float* dbb = (const float*)d_in[4];
  float* out = (float*)d_out;

  char* ws = (char*)d_ws;
  size_t o = 0;
  unsigned short* xb  = (unsigned short*)(ws + o); o += (size_t)cE * cT * cH * 2;        // 128 MiB
  unsigned short* w1t = (unsigned short*)(ws + o); o += (size_t)cE * 2 * cI * cH * 2;    // 128 MiB
  unsigned short* w2t = (unsigned short*)(ws + o); o += (size_t)cE * cH * cI * 2;        //  64 MiB
  unsigned short* hb  = (unsigned short*)(ws + o); o += (size_t)cE * cT * cI * 2;        // 128 MiB
  if (ws_size < o)
    fprintf(stderr, "WS TOO SMALL: need %zu have %zu\n", o, ws_size);

  conv_f2bf<<<2048, 256, 0, stream>>>(x, xb, (size_t)cE * cT * cH);
  transpose_conv<<<dim3(2 * cI / 32, cH / 32, cE), dim3(32, 8), 0, stream>>>(gup, w1t, cH, 2 * cI, cI);
  transpose_conv<<<dim3(cH / 32, cI / 32, cE), dim3(32, 8), 0, stream>>>(dwn, w2t, cI, cH, 0);
  gemm1_kernel<<<dim3(cI / 128, cT / 128, cE), 256, 0, stream>>>(xb, w1t, gub, hb);
  gemm2_kernel<<<dim3(cH / 128, cT / 128, cE), 256, 0, stream>>>(hb, w2t, dbb, out);
}